// Round 1
// baseline (1071.748 us; speedup 1.0000x reference)
//
#include <hip/hip_runtime.h>
#include <stdint.h>

#define Nn 2404
#define Bb 4
#define NP 2560      // padded j (cols), multiple of 512 (5 passes of 64 lanes x 8)
#define NR 2432      // padded i (rows)
#define HOPS 76      // DEMAND_HOP + 1
#define RPB 20       // rows per block
#define CHUNKS 121   // ceil(2404/20)

__device__ __forceinline__ float bflo(uint32_t u){ return __uint_as_float(u << 16); }
__device__ __forceinline__ float bfhi(uint32_t u){ return __uint_as_float(u & 0xffff0000u); }
__device__ __forceinline__ uint16_t f2bf(float f){
    uint32_t u = __float_as_uint(f);
    u = u + 0x7fffu + ((u >> 16) & 1u);   // RNE
    return (uint16_t)(u >> 16);
}

// ---- transpose fp32 NxN -> bf16 NR x NP (dst[i][j] = src[j][i], zero-padded) ----
__global__ __launch_bounds__(256) void k_tr(const float* __restrict__ src, uint16_t* __restrict__ dst)
{
    __shared__ float tile[32][33];
    int tx = threadIdx.x, ty = threadIdx.y;
    int j0 = blockIdx.x * 32, i0 = blockIdx.y * 32;
    #pragma unroll
    for (int m = 0; m < 4; ++m){
        int sj = j0 + ty + m * 8;
        int si = i0 + tx;
        tile[ty + m * 8][tx] = (sj < Nn && si < Nn) ? src[(size_t)sj * Nn + si] : 0.f;
    }
    __syncthreads();
    #pragma unroll
    for (int m = 0; m < 4; ++m){
        int di = i0 + ty + m * 8;
        dst[(size_t)di * NP + j0 + tx] = f2bf(tile[tx][ty + m * 8]);
    }
}

// ---- copy fp32 NxN -> bf16 NR x NP (zero-padded) ----
__global__ __launch_bounds__(256) void k_cp(const float* __restrict__ src, uint16_t* __restrict__ dst)
{
    int j = blockIdx.x * 256 + threadIdx.x;
    int i = blockIdx.y;
    dst[(size_t)i * NP + j] = (i < Nn && j < Nn) ? f2bf(src[(size_t)i * Nn + j]) : (uint16_t)0;
}

// ---- init col buffers, y ping-pong, Hs, base ----
__global__ __launch_bounds__(256) void k_prep(const float* __restrict__ X, const float* __restrict__ ToD,
    const float* __restrict__ DoW, const float* __restrict__ ow, const float* __restrict__ ob,
    float* __restrict__ L1, float* __restrict__ L2, float* __restrict__ L3,
    float* __restrict__ base, float* __restrict__ y0, float* __restrict__ y1, float* __restrict__ Hs)
{
    int j = blockIdx.x * 256 + threadIdx.x;   // < NP
    int b = blockIdx.y;
    float x = (j < Nn) ? X[b * Nn + j] : 0.f;
    #pragma unroll
    for (int c = 0; c < 3; ++c)  L1[((size_t)(c * Bb + b)) * NP + j] = (c == 0) ? x : 0.f;
    #pragma unroll
    for (int c = 0; c < 7; ++c)  L2[((size_t)(c * Bb + b)) * NP + j] = (c == 0) ? x : 0.f;
    #pragma unroll
    for (int c = 0; c < 15; ++c) L3[((size_t)(c * Bb + b)) * NP + j] = (c == 0) ? x : 0.f;
    y0[b * NP + j] = x;
    y1[b * NP + j] = 0.f;
    if (j < NR) Hs[b * NR + j] = 0.f;
    if (b == 0 && j < NR){
        float v = 0.f;
        if (j < Nn){
            v = ob[j];
            #pragma unroll
            for (int t = 0; t < 24; ++t) v = fmaf(ToD[j * 24 + t], ow[j * 29 + 4 + t], v);
            v = fmaf(DoW[j], ow[j * 29 + 28], v);
        }
        base[j] = v;
    }
}

// ---- dual-prop step: out[(c*Bb+b)][row] = dot(M[row,:], in[(c*Bb+b)][:]) ----
template<int CIN>
__global__ __launch_bounds__(256) void k_dual(const uint16_t* __restrict__ M,
    const float* __restrict__ in, float* __restrict__ out)
{
    int bid = blockIdx.x;
    int b = bid / CHUNKS, chunk = bid % CHUNKS;
    int r0 = chunk * RPB;
    int wave = threadIdx.x >> 6, lane = threadIdx.x & 63;
    for (int rr = 0; rr < RPB / 4; ++rr){
        int row = r0 + rr * 4 + wave;          // <= 2419 < NR
        const uint16_t* mr = M + (size_t)row * NP;
        float af[40];
        #pragma unroll
        for (int p = 0; p < 5; ++p){
            uint4 av = *(const uint4*)(mr + p * 512 + lane * 8);
            af[p*8+0]=bflo(av.x); af[p*8+1]=bfhi(av.x);
            af[p*8+2]=bflo(av.y); af[p*8+3]=bfhi(av.y);
            af[p*8+4]=bflo(av.z); af[p*8+5]=bfhi(av.z);
            af[p*8+6]=bflo(av.w); af[p*8+7]=bfhi(av.w);
        }
        float acc[CIN];
        #pragma unroll
        for (int c = 0; c < CIN; ++c) acc[c] = 0.f;
        #pragma unroll
        for (int p = 0; p < 5; ++p){
            #pragma unroll
            for (int c = 0; c < CIN; ++c){
                const float* ib = in + ((size_t)(c * Bb + b)) * NP + p * 512 + lane * 8;
                float4 u0 = *(const float4*)(ib);
                float4 u1 = *(const float4*)(ib + 4);
                acc[c] = fmaf(af[p*8+0], u0.x, acc[c]);
                acc[c] = fmaf(af[p*8+1], u0.y, acc[c]);
                acc[c] = fmaf(af[p*8+2], u0.z, acc[c]);
                acc[c] = fmaf(af[p*8+3], u0.w, acc[c]);
                acc[c] = fmaf(af[p*8+4], u1.x, acc[c]);
                acc[c] = fmaf(af[p*8+5], u1.y, acc[c]);
                acc[c] = fmaf(af[p*8+6], u1.z, acc[c]);
                acc[c] = fmaf(af[p*8+7], u1.w, acc[c]);
            }
        }
        #pragma unroll
        for (int c = 0; c < CIN; ++c){
            float v = acc[c];
            #pragma unroll
            for (int off = 32; off; off >>= 1) v += __shfl_down(v, off, 64);
            if (lane == 0) out[((size_t)(c * Bb + b)) * NP + row] = v;
        }
    }
}

// ---- attention logits + softmax over 76 hops; one wave per (b,n) ----
__global__ __launch_bounds__(256) void k_att(const float* __restrict__ S,
    const float* __restrict__ att_w, const float* __restrict__ att_b, float* __restrict__ P)
{
    int wave = threadIdx.x >> 6, lane = threadIdx.x & 63;
    int idx = blockIdx.x * 4 + wave;          // < 9616
    int b = idx / Nn, n = idx % Nn;
    float s[15];
    #pragma unroll
    for (int c = 0; c < 15; ++c) s[c] = S[((size_t)(c * Bb + b)) * NP + n];
    int o1 = lane, o2 = lane + 64;
    const float* aw = att_w + (size_t)n * 15 * HOPS;
    float a1 = att_b[(size_t)n * HOPS + o1];
    #pragma unroll
    for (int c = 0; c < 15; ++c) a1 = fmaf(s[c], aw[c * HOPS + o1], a1);
    float a2 = -1e30f;
    if (o2 < HOPS){
        a2 = att_b[(size_t)n * HOPS + o2];
        #pragma unroll
        for (int c = 0; c < 15; ++c) a2 = fmaf(s[c], aw[c * HOPS + o2], a2);
    }
    float m = fmaxf(a1, a2);
    #pragma unroll
    for (int off = 32; off; off >>= 1) m = fmaxf(m, __shfl_xor(m, off, 64));
    float e1 = __expf(a1 - m);
    float e2 = (o2 < HOPS) ? __expf(a2 - m) : 0.f;
    float t = e1 + e2;
    #pragma unroll
    for (int off = 32; off; off >>= 1) t += __shfl_xor(t, off, 64);
    float inv = 1.f / t;
    P[((size_t)(b * HOPS + o1)) * NR + n] = e1 * inv;
    if (o2 < HOPS) P[((size_t)(b * HOPS + o2)) * NR + n] = e2 * inv;
}

// ---- Hs init with hop-0 term ----
__global__ __launch_bounds__(256) void k_hs0(const float* __restrict__ X, const float* __restrict__ P,
                                             float* __restrict__ Hs)
{
    int i = blockIdx.x * 256 + threadIdx.x;
    int b = blockIdx.y;
    if (i < NR) Hs[b * NR + i] = (i < Nn) ? P[((size_t)(b * HOPS)) * NR + i] * X[b * Nn + i] : 0.f;
}

// ---- one demand-chain hop: ynext = A @ ycur (bf16 A, fp32 acc), Hs += P[:,k]*ynext ----
__global__ __launch_bounds__(256) void k_step(const uint16_t* __restrict__ At,
    const float* __restrict__ ycur, float* __restrict__ ynext,
    const float* __restrict__ P, float* __restrict__ Hs, int k)
{
    int bid = blockIdx.x;
    int b = bid / CHUNKS, chunk = bid % CHUNKS;
    int r0 = chunk * RPB;
    int wave = threadIdx.x >> 6, lane = threadIdx.x & 63;
    const float* yb = ycur + b * NP;
    float yv[40];
    #pragma unroll
    for (int p = 0; p < 5; ++p){
        float4 u0 = *(const float4*)(yb + p * 512 + lane * 8);
        float4 u1 = *(const float4*)(yb + p * 512 + lane * 8 + 4);
        yv[p*8+0]=u0.x; yv[p*8+1]=u0.y; yv[p*8+2]=u0.z; yv[p*8+3]=u0.w;
        yv[p*8+4]=u1.x; yv[p*8+5]=u1.y; yv[p*8+6]=u1.z; yv[p*8+7]=u1.w;
    }
    #pragma unroll
    for (int rr = 0; rr < RPB / 4; ++rr){
        int row = r0 + rr * 4 + wave;          // <= 2419 < NR
        const uint16_t* ar = At + ((size_t)(b * NR + row)) * NP;
        float acc = 0.f;
        #pragma unroll
        for (int p = 0; p < 5; ++p){
            uint4 av = *(const uint4*)(ar + p * 512 + lane * 8);
            acc = fmaf(bflo(av.x), yv[p*8+0], acc);
            acc = fmaf(bfhi(av.x), yv[p*8+1], acc);
            acc = fmaf(bflo(av.y), yv[p*8+2], acc);
            acc = fmaf(bfhi(av.y), yv[p*8+3], acc);
            acc = fmaf(bflo(av.z), yv[p*8+4], acc);
            acc = fmaf(bfhi(av.z), yv[p*8+5], acc);
            acc = fmaf(bflo(av.w), yv[p*8+6], acc);
            acc = fmaf(bfhi(av.w), yv[p*8+7], acc);
        }
        #pragma unroll
        for (int off = 32; off; off >>= 1) acc += __shfl_down(acc, off, 64);
        if (lane == 0){
            ynext[b * NP + row] = acc;
            Hs[b * NR + row] += P[((size_t)(b * HOPS + k)) * NR + row] * acc;
        }
    }
}

// ---- epilogue: Y[i] = base[i] + sum_b Hs[b][i] * out_w[i][b] ----
__global__ __launch_bounds__(256) void k_final(const float* __restrict__ Hs, const float* __restrict__ base,
    const float* __restrict__ ow, float* __restrict__ Y)
{
    int i = blockIdx.x * 256 + threadIdx.x;
    if (i < Nn){
        float v = base[i];
        #pragma unroll
        for (int b = 0; b < Bb; ++b) v = fmaf(Hs[b * NR + i], ow[i * 29 + b], v);
        Y[i] = v;
    }
}

extern "C" void kernel_launch(void* const* d_in, const int* in_sizes, int n_in,
                              void* d_out, int out_size, void* d_ws, size_t ws_size,
                              hipStream_t stream)
{
    const float* X     = (const float*)d_in[0];
    const float* T     = (const float*)d_in[1];
    const float* Wnorm = (const float*)d_in[4];
    const float* ToD   = (const float*)d_in[5];
    const float* DoW   = (const float*)d_in[6];
    const float* att_w = (const float*)d_in[7];
    const float* att_b = (const float*)d_in[8];
    const float* out_w = (const float*)d_in[9];
    const float* out_b = (const float*)d_in[10];
    float* Y = (float*)d_out;

    char* ws = (char*)d_ws;
    size_t off = 0;
    auto alloc = [&](size_t bytes){ void* p = ws + off; off += (bytes + 255) & ~(size_t)255; return p; };
    uint16_t* At  = (uint16_t*)alloc((size_t)Bb * NR * NP * 2);
    uint16_t* Wn  = (uint16_t*)alloc((size_t)NR * NP * 2);
    uint16_t* Wnt = (uint16_t*)alloc((size_t)NR * NP * 2);
    float* L1 = (float*)alloc((size_t)3  * Bb * NP * 4);
    float* L2 = (float*)alloc((size_t)7  * Bb * NP * 4);
    float* L3 = (float*)alloc((size_t)15 * Bb * NP * 4);
    float* P  = (float*)alloc((size_t)Bb * HOPS * NR * 4);
    float* y0 = (float*)alloc((size_t)Bb * NP * 4);
    float* y1 = (float*)alloc((size_t)Bb * NP * 4);
    float* Hs = (float*)alloc((size_t)Bb * NR * 4);
    float* base = (float*)alloc((size_t)NR * 4);
    (void)ws_size; (void)in_sizes; (void)n_in; (void)out_size;

    // stage inputs: At[b] = T[b]^T (bf16, padded), Wn = W_norm, Wnt = W_norm^T
    for (int b = 0; b < Bb; ++b)
        k_tr<<<dim3(NP / 32, NR / 32), dim3(32, 8), 0, stream>>>(T + (size_t)b * Nn * Nn, At + (size_t)b * NR * NP);
    k_cp<<<dim3(NP / 256, NR), 256, 0, stream>>>(Wnorm, Wn);
    k_tr<<<dim3(NP / 32, NR / 32), dim3(32, 8), 0, stream>>>(Wnorm, Wnt);
    k_prep<<<dim3(NP / 256, Bb), 256, 0, stream>>>(X, ToD, DoW, out_w, out_b, L1, L2, L3, base, y0, y1, Hs);

    // dual propagation: L1 = [y, Ay, Ty]; L2 = [y, A@L1, T@L1]; L3 = [y, A@L2, T@L2]
    k_dual<1><<<Bb * CHUNKS, 256, 0, stream>>>(Wn,  L1, L1 + (size_t)1 * Bb * NP);
    k_dual<1><<<Bb * CHUNKS, 256, 0, stream>>>(Wnt, L1, L1 + (size_t)2 * Bb * NP);
    k_dual<3><<<Bb * CHUNKS, 256, 0, stream>>>(Wn,  L1, L2 + (size_t)1 * Bb * NP);
    k_dual<3><<<Bb * CHUNKS, 256, 0, stream>>>(Wnt, L1, L2 + (size_t)4 * Bb * NP);
    k_dual<7><<<Bb * CHUNKS, 256, 0, stream>>>(Wn,  L2, L3 + (size_t)1 * Bb * NP);
    k_dual<7><<<Bb * CHUNKS, 256, 0, stream>>>(Wnt, L2, L3 + (size_t)8 * Bb * NP);

    // attention softmax P[b][hop][n], Hs hop-0 term
    k_att<<<Nn, 256, 0, stream>>>(L3, att_w, att_b, P);
    k_hs0<<<dim3((NR + 255) / 256, Bb), 256, 0, stream>>>(X, P, Hs);

    // 75 sequential hops, fused Hs accumulation
    float* yb[2] = { y0, y1 };
    for (int k = 1; k <= 75; ++k)
        k_step<<<Bb * CHUNKS, 256, 0, stream>>>(At, yb[(k + 1) & 1], yb[k & 1], P, Hs, k);

    k_final<<<(Nn + 255) / 256, 256, 0, stream>>>(Hs, base, out_w, Y);
}

// Round 2
// 1063.395 us; speedup vs baseline: 1.0079x; 1.0079x over previous
//
#include <hip/hip_runtime.h>
#include <stdint.h>

#define Nn 2404
#define Bb 4
#define NP 2560      // padded stride for dual-prop buffers (5 x 512)
#define NK 2432      // tight padded stride for demand chain (4 x 512 + 384)
#define NR 2432      // padded rows
#define HOPS 76      // DEMAND_HOP + 1
#define RPB 8        // rows per block in k_step (2 rows per wave, concurrent)
#define KCHUNKS 304  // NR / RPB
#define DRPB 20      // rows per block in k_dual
#define DCHUNKS 121  // ceil(Nn/DRPB)

__device__ __forceinline__ float bflo(uint32_t u){ return __uint_as_float(u << 16); }
__device__ __forceinline__ float bfhi(uint32_t u){ return __uint_as_float(u & 0xffff0000u); }
__device__ __forceinline__ uint16_t f2bf(float f){
    uint32_t u = __float_as_uint(f);
    u = u + 0x7fffu + ((u >> 16) & 1u);   // RNE
    return (uint16_t)(u >> 16);
}

// ---- transpose fp32 NxN -> bf16 NR x stride (dst[i][j] = src[j][i], zero-padded) ----
__global__ __launch_bounds__(256) void k_tr(const float* __restrict__ src, uint16_t* __restrict__ dst,
                                            int dstride)
{
    __shared__ float tile[32][33];
    int tx = threadIdx.x, ty = threadIdx.y;
    int j0 = blockIdx.x * 32, i0 = blockIdx.y * 32;
    #pragma unroll
    for (int m = 0; m < 4; ++m){
        int sj = j0 + ty + m * 8;
        int si = i0 + tx;
        tile[ty + m * 8][tx] = (sj < Nn && si < Nn) ? src[(size_t)sj * Nn + si] : 0.f;
    }
    __syncthreads();
    #pragma unroll
    for (int m = 0; m < 4; ++m){
        int di = i0 + ty + m * 8;
        dst[(size_t)di * dstride + j0 + tx] = f2bf(tile[tx][ty + m * 8]);
    }
}

// ---- copy fp32 NxN -> bf16 NR x NP (zero-padded) ----
__global__ __launch_bounds__(256) void k_cp(const float* __restrict__ src, uint16_t* __restrict__ dst)
{
    int j = blockIdx.x * 256 + threadIdx.x;
    int i = blockIdx.y;
    dst[(size_t)i * NP + j] = (i < Nn && j < Nn) ? f2bf(src[(size_t)i * Nn + j]) : (uint16_t)0;
}

// ---- init col buffers, y ping-pong, Hs, base ----
__global__ __launch_bounds__(256) void k_prep(const float* __restrict__ X, const float* __restrict__ ToD,
    const float* __restrict__ DoW, const float* __restrict__ ow, const float* __restrict__ ob,
    float* __restrict__ L1, float* __restrict__ L2, float* __restrict__ L3,
    float* __restrict__ base, float* __restrict__ y0, float* __restrict__ y1, float* __restrict__ Hs)
{
    int j = blockIdx.x * 256 + threadIdx.x;   // < NP
    int b = blockIdx.y;
    float x = (j < Nn) ? X[b * Nn + j] : 0.f;
    #pragma unroll
    for (int c = 0; c < 3; ++c)  L1[((size_t)(c * Bb + b)) * NP + j] = (c == 0) ? x : 0.f;
    #pragma unroll
    for (int c = 0; c < 7; ++c)  L2[((size_t)(c * Bb + b)) * NP + j] = (c == 0) ? x : 0.f;
    #pragma unroll
    for (int c = 0; c < 15; ++c) L3[((size_t)(c * Bb + b)) * NP + j] = (c == 0) ? x : 0.f;
    if (j < NK){
        y0[b * NK + j] = x;
        y1[b * NK + j] = 0.f;
    }
    if (j < NR) Hs[b * NR + j] = 0.f;
    if (b == 0 && j < NR){
        float v = 0.f;
        if (j < Nn){
            v = ob[j];
            #pragma unroll
            for (int t = 0; t < 24; ++t) v = fmaf(ToD[j * 24 + t], ow[j * 29 + 4 + t], v);
            v = fmaf(DoW[j], ow[j * 29 + 28], v);
        }
        base[j] = v;
    }
}

// ---- dual-prop step: out[(c*Bb+b)][row] = dot(M[row,:], in[(c*Bb+b)][:]) ----
template<int CIN>
__global__ __launch_bounds__(256) void k_dual(const uint16_t* __restrict__ M,
    const float* __restrict__ in, float* __restrict__ out)
{
    int bid = blockIdx.x;
    int b = bid / DCHUNKS, chunk = bid % DCHUNKS;
    int r0 = chunk * DRPB;
    int wave = threadIdx.x >> 6, lane = threadIdx.x & 63;
    for (int rr = 0; rr < DRPB / 4; ++rr){
        int row = r0 + rr * 4 + wave;          // <= 2419 < NR
        const uint16_t* mr = M + (size_t)row * NP;
        float af[40];
        #pragma unroll
        for (int p = 0; p < 5; ++p){
            uint4 av = *(const uint4*)(mr + p * 512 + lane * 8);
            af[p*8+0]=bflo(av.x); af[p*8+1]=bfhi(av.x);
            af[p*8+2]=bflo(av.y); af[p*8+3]=bfhi(av.y);
            af[p*8+4]=bflo(av.z); af[p*8+5]=bfhi(av.z);
            af[p*8+6]=bflo(av.w); af[p*8+7]=bfhi(av.w);
        }
        float acc[CIN];
        #pragma unroll
        for (int c = 0; c < CIN; ++c) acc[c] = 0.f;
        #pragma unroll
        for (int p = 0; p < 5; ++p){
            #pragma unroll
            for (int c = 0; c < CIN; ++c){
                const float* ib = in + ((size_t)(c * Bb + b)) * NP + p * 512 + lane * 8;
                float4 u0 = *(const float4*)(ib);
                float4 u1 = *(const float4*)(ib + 4);
                acc[c] = fmaf(af[p*8+0], u0.x, acc[c]);
                acc[c] = fmaf(af[p*8+1], u0.y, acc[c]);
                acc[c] = fmaf(af[p*8+2], u0.z, acc[c]);
                acc[c] = fmaf(af[p*8+3], u0.w, acc[c]);
                acc[c] = fmaf(af[p*8+4], u1.x, acc[c]);
                acc[c] = fmaf(af[p*8+5], u1.y, acc[c]);
                acc[c] = fmaf(af[p*8+6], u1.z, acc[c]);
                acc[c] = fmaf(af[p*8+7], u1.w, acc[c]);
            }
        }
        #pragma unroll
        for (int c = 0; c < CIN; ++c){
            float v = acc[c];
            #pragma unroll
            for (int off = 32; off; off >>= 1) v += __shfl_down(v, off, 64);
            if (lane == 0) out[((size_t)(c * Bb + b)) * NP + row] = v;
        }
    }
}

// ---- attention logits + softmax over 76 hops; one wave per (b,n) ----
__global__ __launch_bounds__(256) void k_att(const float* __restrict__ S,
    const float* __restrict__ att_w, const float* __restrict__ att_b, float* __restrict__ P)
{
    int wave = threadIdx.x >> 6, lane = threadIdx.x & 63;
    int idx = blockIdx.x * 4 + wave;          // < 9616
    int b = idx / Nn, n = idx % Nn;
    float s[15];
    #pragma unroll
    for (int c = 0; c < 15; ++c) s[c] = S[((size_t)(c * Bb + b)) * NP + n];
    int o1 = lane, o2 = lane + 64;
    const float* aw = att_w + (size_t)n * 15 * HOPS;
    float a1 = att_b[(size_t)n * HOPS + o1];
    #pragma unroll
    for (int c = 0; c < 15; ++c) a1 = fmaf(s[c], aw[c * HOPS + o1], a1);
    float a2 = -1e30f;
    if (o2 < HOPS){
        a2 = att_b[(size_t)n * HOPS + o2];
        #pragma unroll
        for (int c = 0; c < 15; ++c) a2 = fmaf(s[c], aw[c * HOPS + o2], a2);
    }
    float m = fmaxf(a1, a2);
    #pragma unroll
    for (int off = 32; off; off >>= 1) m = fmaxf(m, __shfl_xor(m, off, 64));
    float e1 = __expf(a1 - m);
    float e2 = (o2 < HOPS) ? __expf(a2 - m) : 0.f;
    float t = e1 + e2;
    #pragma unroll
    for (int off = 32; off; off >>= 1) t += __shfl_xor(t, off, 64);
    float inv = 1.f / t;
    P[((size_t)(b * HOPS + o1)) * NR + n] = e1 * inv;
    if (o2 < HOPS) P[((size_t)(b * HOPS + o2)) * NR + n] = e2 * inv;
}

// ---- Hs init with hop-0 term ----
__global__ __launch_bounds__(256) void k_hs0(const float* __restrict__ X, const float* __restrict__ P,
                                             float* __restrict__ Hs)
{
    int i = blockIdx.x * 256 + threadIdx.x;
    int b = blockIdx.y;
    if (i < NR) Hs[b * NR + i] = (i < Nn) ? P[((size_t)(b * HOPS)) * NR + i] * X[b * Nn + i] : 0.f;
}

// ---- one demand-chain hop: ynext = A @ ycur (bf16 A, fp32 acc), Hs += P[:,k]*ynext ----
// grid: Bb * KCHUNKS blocks, 256 threads. Each wave handles 2 rows concurrently
// (10 independent 16B A-loads in flight). y staged via LDS -> 40 regs per lane.
__global__ __launch_bounds__(256, 4) void k_step(const uint16_t* __restrict__ At,
    const float* __restrict__ ycur, float* __restrict__ ynext,
    const float* __restrict__ P, float* __restrict__ Hs, int k)
{
    __shared__ float ysh[NK];
    int bid = blockIdx.x;
    int b = bid / KCHUNKS, chunk = bid % KCHUNKS;
    int r0 = chunk * RPB;
    const float* yb = ycur + b * NK;
    // cooperative y -> LDS (NK/4 = 608 float4)
    for (int i = threadIdx.x; i < NK / 4; i += 256)
        ((float4*)ysh)[i] = ((const float4*)yb)[i];
    __syncthreads();

    int wave = threadIdx.x >> 6, lane = threadIdx.x & 63;
    // y fragment -> registers (reused for both rows)
    float yv[40];
    #pragma unroll
    for (int p = 0; p < 4; ++p){
        float4 u0 = *(const float4*)(ysh + p * 512 + lane * 8);
        float4 u1 = *(const float4*)(ysh + p * 512 + lane * 8 + 4);
        yv[p*8+0]=u0.x; yv[p*8+1]=u0.y; yv[p*8+2]=u0.z; yv[p*8+3]=u0.w;
        yv[p*8+4]=u1.x; yv[p*8+5]=u1.y; yv[p*8+6]=u1.z; yv[p*8+7]=u1.w;
    }
    bool tail = (lane < 48);                   // partial pass: cols 2048..2431
    int c4 = tail ? (2048 + lane * 8) : (NK - 8);  // clamped, always in-row
    {
        float4 u0 = *(const float4*)(ysh + c4);
        float4 u1 = *(const float4*)(ysh + c4 + 4);
        yv[32]=tail?u0.x:0.f; yv[33]=tail?u0.y:0.f; yv[34]=tail?u0.z:0.f; yv[35]=tail?u0.w:0.f;
        yv[36]=tail?u1.x:0.f; yv[37]=tail?u1.y:0.f; yv[38]=tail?u1.z:0.f; yv[39]=tail?u1.w:0.f;
    }

    int r1 = r0 + wave, r2 = r0 + wave + 4;    // < NR
    const uint16_t* ar1 = At + ((size_t)(b * NR + r1)) * NK;
    const uint16_t* ar2 = At + ((size_t)(b * NR + r2)) * NK;
    uint4 av1[5], av2[5];
    #pragma unroll
    for (int p = 0; p < 4; ++p){
        av1[p] = *(const uint4*)(ar1 + p * 512 + lane * 8);
        av2[p] = *(const uint4*)(ar2 + p * 512 + lane * 8);
    }
    av1[4] = *(const uint4*)(ar1 + c4);
    av2[4] = *(const uint4*)(ar2 + c4);

    float acc1 = 0.f, acc2 = 0.f;
    #pragma unroll
    for (int p = 0; p < 5; ++p){
        acc1 = fmaf(bflo(av1[p].x), yv[p*8+0], acc1);
        acc2 = fmaf(bflo(av2[p].x), yv[p*8+0], acc2);
        acc1 = fmaf(bfhi(av1[p].x), yv[p*8+1], acc1);
        acc2 = fmaf(bfhi(av2[p].x), yv[p*8+1], acc2);
        acc1 = fmaf(bflo(av1[p].y), yv[p*8+2], acc1);
        acc2 = fmaf(bflo(av2[p].y), yv[p*8+2], acc2);
        acc1 = fmaf(bfhi(av1[p].y), yv[p*8+3], acc1);
        acc2 = fmaf(bfhi(av2[p].y), yv[p*8+3], acc2);
        acc1 = fmaf(bflo(av1[p].z), yv[p*8+4], acc1);
        acc2 = fmaf(bflo(av2[p].z), yv[p*8+4], acc2);
        acc1 = fmaf(bfhi(av1[p].z), yv[p*8+5], acc1);
        acc2 = fmaf(bfhi(av2[p].z), yv[p*8+5], acc2);
        acc1 = fmaf(bflo(av1[p].w), yv[p*8+6], acc1);
        acc2 = fmaf(bflo(av2[p].w), yv[p*8+6], acc2);
        acc1 = fmaf(bfhi(av1[p].w), yv[p*8+7], acc1);
        acc2 = fmaf(bfhi(av2[p].w), yv[p*8+7], acc2);
    }
    #pragma unroll
    for (int off = 32; off; off >>= 1){
        acc1 += __shfl_down(acc1, off, 64);
        acc2 += __shfl_down(acc2, off, 64);
    }
    if (lane == 0){
        ynext[b * NK + r1] = acc1;
        Hs[b * NR + r1] += P[((size_t)(b * HOPS + k)) * NR + r1] * acc1;
        ynext[b * NK + r2] = acc2;
        Hs[b * NR + r2] += P[((size_t)(b * HOPS + k)) * NR + r2] * acc2;
    }
}

// ---- epilogue: Y[i] = base[i] + sum_b Hs[b][i] * out_w[i][b] ----
__global__ __launch_bounds__(256) void k_final(const float* __restrict__ Hs, const float* __restrict__ base,
    const float* __restrict__ ow, float* __restrict__ Y)
{
    int i = blockIdx.x * 256 + threadIdx.x;
    if (i < Nn){
        float v = base[i];
        #pragma unroll
        for (int b = 0; b < Bb; ++b) v = fmaf(Hs[b * NR + i], ow[i * 29 + b], v);
        Y[i] = v;
    }
}

extern "C" void kernel_launch(void* const* d_in, const int* in_sizes, int n_in,
                              void* d_out, int out_size, void* d_ws, size_t ws_size,
                              hipStream_t stream)
{
    const float* X     = (const float*)d_in[0];
    const float* T     = (const float*)d_in[1];
    const float* Wnorm = (const float*)d_in[4];
    const float* ToD   = (const float*)d_in[5];
    const float* DoW   = (const float*)d_in[6];
    const float* att_w = (const float*)d_in[7];
    const float* att_b = (const float*)d_in[8];
    const float* out_w = (const float*)d_in[9];
    const float* out_b = (const float*)d_in[10];
    float* Y = (float*)d_out;

    char* ws = (char*)d_ws;
    size_t off = 0;
    auto alloc = [&](size_t bytes){ void* p = ws + off; off += (bytes + 255) & ~(size_t)255; return p; };
    uint16_t* At  = (uint16_t*)alloc((size_t)Bb * NR * NK * 2 + 512);  // tight stride + slack
    uint16_t* Wn  = (uint16_t*)alloc((size_t)NR * NP * 2);
    uint16_t* Wnt = (uint16_t*)alloc((size_t)NR * NP * 2);
    float* L1 = (float*)alloc((size_t)3  * Bb * NP * 4);
    float* L2 = (float*)alloc((size_t)7  * Bb * NP * 4);
    float* L3 = (float*)alloc((size_t)15 * Bb * NP * 4);
    float* P  = (float*)alloc((size_t)Bb * HOPS * NR * 4);
    float* y0 = (float*)alloc((size_t)Bb * NK * 4);
    float* y1 = (float*)alloc((size_t)Bb * NK * 4);
    float* Hs = (float*)alloc((size_t)Bb * NR * 4);
    float* base = (float*)alloc((size_t)NR * 4);
    (void)ws_size; (void)in_sizes; (void)n_in; (void)out_size;

    // stage inputs: At[b] = T[b]^T (bf16, stride NK), Wn = W_norm, Wnt = W_norm^T (stride NP)
    for (int b = 0; b < Bb; ++b)
        k_tr<<<dim3(NK / 32, NR / 32), dim3(32, 8), 0, stream>>>(T + (size_t)b * Nn * Nn, At + (size_t)b * NR * NK, NK);
    k_cp<<<dim3(NP / 256, NR), 256, 0, stream>>>(Wnorm, Wn);
    k_tr<<<dim3(NP / 32, NR / 32), dim3(32, 8), 0, stream>>>(Wnorm, Wnt, NP);
    k_prep<<<dim3(NP / 256, Bb), 256, 0, stream>>>(X, ToD, DoW, out_w, out_b, L1, L2, L3, base, y0, y1, Hs);

    // dual propagation: L1 = [y, Ay, Ty]; L2 = [y, A@L1, T@L1]; L3 = [y, A@L2, T@L2]
    k_dual<1><<<Bb * DCHUNKS, 256, 0, stream>>>(Wn,  L1, L1 + (size_t)1 * Bb * NP);
    k_dual<1><<<Bb * DCHUNKS, 256, 0, stream>>>(Wnt, L1, L1 + (size_t)2 * Bb * NP);
    k_dual<3><<<Bb * DCHUNKS, 256, 0, stream>>>(Wn,  L1, L2 + (size_t)1 * Bb * NP);
    k_dual<3><<<Bb * DCHUNKS, 256, 0, stream>>>(Wnt, L1, L2 + (size_t)4 * Bb * NP);
    k_dual<7><<<Bb * DCHUNKS, 256, 0, stream>>>(Wn,  L2, L3 + (size_t)1 * Bb * NP);
    k_dual<7><<<Bb * DCHUNKS, 256, 0, stream>>>(Wnt, L2, L3 + (size_t)8 * Bb * NP);

    // attention softmax P[b][hop][n], Hs hop-0 term
    k_att<<<Nn, 256, 0, stream>>>(L3, att_w, att_b, P);
    k_hs0<<<dim3((NR + 255) / 256, Bb), 256, 0, stream>>>(X, P, Hs);

    // 75 sequential hops, fused Hs accumulation
    float* yb[2] = { y0, y1 };
    for (int k = 1; k <= 75; ++k)
        k_step<<<Bb * KCHUNKS, 256, 0, stream>>>(At, yb[(k + 1) & 1], yb[k & 1], P, Hs, k);

    k_final<<<(Nn + 255) / 256, 256, 0, stream>>>(Hs, base, out_w, Y);
}